// Round 10
// baseline (114.056 us; speedup 1.0000x reference)
//
#include <hip/hip_runtime.h>
#include <hip/hip_bf16.h>

#define BB 8
#define NN 2048
#define FF 128

typedef short bh8 __attribute__((ext_vector_type(8)));
typedef float fl4 __attribute__((ext_vector_type(4)));
typedef unsigned short u16;
typedef unsigned long long u64;
typedef union { bh8 v; unsigned u[4]; } bh8u;

__device__ __forceinline__ u16 f2bf(float x) {
    unsigned u = __float_as_uint(x);
    return (u16)((u + 0x7FFFu + ((u >> 16) & 1u)) >> 16);
}

__device__ __forceinline__ void loadB(bh8 (&buf)[8], const u16* hB, int lr, int kbase) {
    #pragma unroll
    for (int ct = 0; ct < 8; ++ct)
        buf[ct] = *(const bh8*)(hB + (ct * 16 + lr) * NN + kbase);
}

// ---------------------------------------------------------------------------
// kernel 1: adjacency bit-pack via ballot (R6 version — best measured).
// ---------------------------------------------------------------------------
__global__ __launch_bounds__(256) void k_pack(
    const int* __restrict__ adj, u64* __restrict__ bm)
{
    const int t = threadIdx.x;
    const int w = t >> 6, lane = t & 63;
    const long row0 = (long)blockIdx.x * 8;
    #pragma unroll 8
    for (int i = 0; i < 64; ++i) {
        const int row = 2 * w + (i >> 5);
        const int chunk = i & 31;
        const int av = adj[(row0 + row) * NN + chunk * 64 + lane];
        const u64 m64 = __ballot(av > 0);
        if (lane == 0) bm[(row0 + row) * 32 + chunk] = m64;
    }
}

// ---------------------------------------------------------------------------
// kernel 2: h = feat @ W + b -> htg bf16 transposed [b][o][n]; esrc, edst.
// ---------------------------------------------------------------------------
__global__ __launch_bounds__(256) void k_h(
    const float* __restrict__ feat, const float* __restrict__ W,
    const float* __restrict__ bias, const float* __restrict__ a,
    u16* __restrict__ htg, float* __restrict__ esrc, float* __restrict__ edst)
{
    __shared__ float fsh[8][FF];
    __shared__ float red[2][2][8];
    const int t = threadIdx.x;
    const long row0 = (long)blockIdx.x * 8;

    ((float4*)&fsh[0][0])[t] = ((const float4*)(feat + row0 * FF))[t];
    __syncthreads();

    const int o = t & 127;
    const int half = t >> 7;
    float acc[4] = {0.f, 0.f, 0.f, 0.f};
    #pragma unroll 4
    for (int k = 0; k < FF; ++k) {
        const float w = W[k * FF + o];
        #pragma unroll
        for (int r = 0; r < 4; ++r)
            acc[r] = fmaf(fsh[half * 4 + r][k], w, acc[r]);
    }
    const float bo = bias[o];
    const float as = a[o];
    const float ad = a[FF + o];
    float ps[4], pd[4];
    #pragma unroll
    for (int r = 0; r < 4; ++r) {
        acc[r] += bo;
        ps[r] = acc[r] * as;
        pd[r] = acc[r] * ad;
    }
    {
        const int bI = (int)(row0 >> 11);
        const int nloc = (int)(row0 & 2047) + half * 4;
        ushort4 hv;
        hv.x = f2bf(acc[0]); hv.y = f2bf(acc[1]);
        hv.z = f2bf(acc[2]); hv.w = f2bf(acc[3]);
        *(ushort4*)&htg[((long)bI * FF + o) * NN + nloc] = hv;
    }
    #pragma unroll
    for (int r = 0; r < 4; ++r) {
        #pragma unroll
        for (int off = 32; off > 0; off >>= 1) {
            ps[r] += __shfl_down(ps[r], off, 64);
            pd[r] += __shfl_down(pd[r], off, 64);
        }
    }
    const int wv = (t >> 6) & 1;
    if ((t & 63) == 0) {
        #pragma unroll
        for (int r = 0; r < 4; ++r) {
            red[half][wv][r]     = ps[r];
            red[half][wv][4 + r] = pd[r];
        }
    }
    __syncthreads();
    if (t < 16) {
        const int hh = t >> 3, idx = t & 7;
        const float v = red[hh][0][idx] + red[hh][1][idx];
        const long row = row0 + hh * 4 + (idx & 3);
        if (idx < 4) esrc[row] = v;
        else         edst[row] = v;
    }
}

// ---------------------------------------------------------------------------
// kernel 3: 16-row blocks, 4 waves m-split (wave w owns m in [w*512,w*512+512)).
// Fully-unrolled 16-step pipeline, pure-register dataflow, NO main-loop
// barriers/LDS. Per step: B-frags / edst / bitmask prefetched one step ahead
// into parity-named buffers (all indices compile-time). psum computed by an
// extra MFMA against a ones-fragment (exact sum of rounded bf16 P).
// ~155 VGPR -> __launch_bounds__(256,3): 12 waves/CU, no spills.
// ---------------------------------------------------------------------------
__global__ __launch_bounds__(256, 3) void k_attn(
    const u64* __restrict__ bm, const float* __restrict__ mask,
    const u16* __restrict__ htg, const float* __restrict__ esrc,
    const float* __restrict__ edst, float* __restrict__ out)
{
    __shared__ float accbuf[4][16][FF + 4];   // 33.8 KB
    __shared__ float psum_sh[4][16];

    const int t = threadIdx.x;
    const int b = blockIdx.x & 7;               // batch -> XCD affinity
    const int n0 = (blockIdx.x >> 3) * 16;      // 128 row-tiles per batch
    const int w = t >> 6, lane = t & 63;
    const int lr = lane & 15, g = lane >> 4;

    // per-wave gmax over edst[b][:] (8 KB, L2-hot)
    float gmx = -3.4e38f;
    {
        const float4* edp4 = (const float4*)(edst + b * NN);
        #pragma unroll
        for (int i = 0; i < 8; ++i) {
            const float4 v = edp4[lane + 64 * i];
            gmx = fmaxf(gmx, fmaxf(fmaxf(v.x, v.y), fmaxf(v.z, v.w)));
        }
        #pragma unroll
        for (int off = 32; off > 0; off >>= 1)
            gmx = fmaxf(gmx, __shfl_xor(gmx, off, 64));
    }

    const float es = esrc[b * NN + n0 + lr];     // this lane's P-row constant
    const float mt0 = es + gmx;
    const float M = fmaxf(mt0, 0.01f * mt0);     // leaky(es+gmax) >= rowmax

    const u16*   hB  = htg + (long)b * FF * NN;
    const float* edb = edst + b * NN;
    const uint4* bmrow = (const uint4*)(bm + ((long)b * NN + n0 + lr) * 32);

    const int mq = w * 512;                      // wave's m-quarter base

    fl4 acc[8];
    #pragma unroll
    for (int ct = 0; ct < 8; ++ct) acc[ct] = (fl4){0.f, 0.f, 0.f, 0.f};
    fl4 accs = (fl4){0.f, 0.f, 0.f, 0.f};
    const bh8 ones = {(short)0x3F80, (short)0x3F80, (short)0x3F80, (short)0x3F80,
                      (short)0x3F80, (short)0x3F80, (short)0x3F80, (short)0x3F80};

    // pipeline state (parity-indexed, all indices compile-time after unroll)
    bh8    bfb[2][8];
    float4 edq[2][2];
    uint4  bq[2];

    // prologue: step 0
    loadB(bfb[0], hB, lr, mq + g * 8);
    edq[0][0] = *(const float4*)(edb + mq + g * 8);
    edq[0][1] = *(const float4*)(edb + mq + g * 8 + 4);
    bq[0] = bmrow[w * 4];

    #pragma unroll
    for (int it = 0; it < 4; ++it) {
        #pragma unroll
        for (int kc = 0; kc < 4; ++kc) {
            const int s = it * 4 + kc;
            const int p = s & 1, pn = p ^ 1;

            // prefetch step s+1 (issued before this step's VALU/MFMA)
            if (s < 15) {
                const int sn = s + 1;
                const int basen = mq + (sn >> 2) * 128 + (sn & 3) * 32 + g * 8;
                loadB(bfb[pn], hB, lr, basen);
                edq[pn][0] = *(const float4*)(edb + basen);
                edq[pn][1] = *(const float4*)(edb + basen + 4);
                if ((sn & 3) == 0) bq[(sn >> 2) & 1] = bmrow[w * 4 + (sn >> 2)];
            }

            // build A-fragment: P = bit ? exp(leaky(es+ed)-M) : 0  (rounded bf16)
            const uint4 bqc = bq[it & 1];
            const unsigned q = (kc == 0) ? bqc.x : (kc == 1) ? bqc.y
                             : (kc == 2) ? bqc.z : bqc.w;
            const unsigned by = (q >> (8 * g)) & 0xFFu;
            const float4 e0 = edq[p][0], e1 = edq[p][1];
            const float pe[8] = {e0.x, e0.y, e0.z, e0.w, e1.x, e1.y, e1.z, e1.w};
            bh8u pa;
            #pragma unroll
            for (int jj = 0; jj < 4; ++jj) {
                const int j0 = 2 * jj, j1 = j0 + 1;
                const float x0 = es + pe[j0];
                const float x1 = es + pe[j1];
                const float l0 = fmaxf(x0, 0.01f * x0);
                const float l1 = fmaxf(x1, 0.01f * x1);
                const float v0 = ((by >> j0) & 1u) ? __expf(l0 - M) : 0.f;
                const float v1 = ((by >> j1) & 1u) ? __expf(l1 - M) : 0.f;
                float2 cf; cf.x = v0; cf.y = v1;
                __hip_bfloat162 r2 = __float22bfloat162_rn(cf);
                pa.u[jj] = *reinterpret_cast<unsigned*>(&r2);
            }

            // 8 output MFMAs + 1 ones-MFMA (row-sum of rounded P)
            #pragma unroll
            for (int ct = 0; ct < 8; ++ct)
                acc[ct] = __builtin_amdgcn_mfma_f32_16x16x32_bf16(pa.v, bfb[p][ct], acc[ct], 0, 0, 0);
            accs = __builtin_amdgcn_mfma_f32_16x16x32_bf16(pa.v, ones, accs, 0, 0, 0);
        }
    }

    // publish partials. C/D layout: col = ct*16+lr, row = g*4+reg  [m89/m91]
    if (lr == 0) {
        #pragma unroll
        for (int reg = 0; reg < 4; ++reg)
            psum_sh[w][g * 4 + reg] = accs[reg];
    }
    #pragma unroll
    for (int ct = 0; ct < 8; ++ct)
        #pragma unroll
        for (int reg = 0; reg < 4; ++reg)
            accbuf[w][g * 4 + reg][ct * 16 + lr] = acc[ct][reg];
    __syncthreads();

    // epilogue: sum the 4 m-quarter partials, scale, write (512 f4 / 256 thr)
    #pragma unroll
    for (int rep = 0; rep < 2; ++rep) {
        const int idx = t + 256 * rep;
        const int r = idx >> 5;
        const int c4 = (idx & 31) * 4;
        const float4 s0 = *(const float4*)&accbuf[0][r][c4];
        const float4 s1 = *(const float4*)&accbuf[1][r][c4];
        const float4 s2 = *(const float4*)&accbuf[2][r][c4];
        const float4 s3 = *(const float4*)&accbuf[3][r][c4];
        const float ps = psum_sh[0][r] + psum_sh[1][r] + psum_sh[2][r] + psum_sh[3][r];
        const float sc = mask[b * NN + n0 + r] / ps;
        float4 o;
        o.x = (s0.x + s1.x + s2.x + s3.x) * sc;
        o.y = (s0.y + s1.y + s2.y + s3.y) * sc;
        o.z = (s0.z + s1.z + s2.z + s3.z) * sc;
        o.w = (s0.w + s1.w + s2.w + s3.w) * sc;
        *(float4*)&out[((long)b * NN + n0 + r) * FF + c4] = o;
    }
}

// ---------------------------------------------------------------------------
extern "C" void kernel_launch(void* const* d_in, const int* in_sizes, int n_in,
                              void* d_out, int out_size, void* d_ws, size_t ws_size,
                              hipStream_t stream)
{
    const float* feat = (const float*)d_in[0];
    const int*   adj  = (const int*)d_in[1];
    const float* mask = (const float*)d_in[2];
    const float* W    = (const float*)d_in[3];
    const float* bias = (const float*)d_in[4];
    const float* a    = (const float*)d_in[5];
    float* out = (float*)d_out;

    // ws: htg bf16 [8][128][2048] (4MB) | esrc | edst (f32 64KB each) | bm 4MB
    u16*   htg  = (u16*)d_ws;
    float* esrc = (float*)(htg + (size_t)BB * FF * NN);
    float* edst = esrc + BB * NN;
    u64*   bmp  = (u64*)(edst + BB * NN);

    k_pack<<<BB * NN / 8, 256, 0, stream>>>(adj, bmp);
    k_h   <<<BB * NN / 8, 256, 0, stream>>>(feat, W, bias, a, htg, esrc, edst);
    k_attn<<<BB * (NN / 16), 256, 0, stream>>>(bmp, mask, htg, esrc, edst, out);
}